// Round 9
// baseline (645.405 us; speedup 1.0000x reference)
//
#include <hip/hip_runtime.h>
#include <stdint.h>

#define T_STEPS 4
#define BATCH   8
#define C_IN    64
#define C_OUT   64
#define HH      128
#define WW      128
#define TH      8
#define TW      16

// f32 rounding of math.exp(-0.5)
#define DECAY_F32 0.6065306597126334f

// Weight re-layout: w[co][ci][ky][kx] -> wt[j][ci][co], j = ky*3+kx
__global__ void wt_build_kernel(const float* __restrict__ w, float* __restrict__ wt) {
    int tid = blockIdx.x * blockDim.x + threadIdx.x;
    if (tid >= 9 * C_IN * C_OUT) return;
    int co = tid & 63;
    int ci = (tid >> 6) & 63;
    int j  = tid >> 12;
    wt[tid] = w[(co * C_IN + ci) * 9 + j];
}

// Exact replica of the reference f32 arithmetic (probe-verified):
// acc chain = seq FMA over (ky,kx, ci-innermost); cb = acc+bias; vt = v*DECAY + cb
// (separate rounded mul/add); spike = vt > 1; soft reset.
// ci is processed in halves WITHIN each j (0..31 then 32..63) -> chain order intact.
// Weights double-buffered in LDS via async global_load_lds issued a phase ahead.
__global__ __launch_bounds__(256, 2) void snn_exact_kernel(
    const float* __restrict__ x,    // [T,B,C_IN,H,W]
    const float* __restrict__ wt,   // [9][C_IN][C_OUT]
    const float* __restrict__ bias, // [C_OUT]
    float* __restrict__ out)        // [T,B,C_OUT,H,W]
{
    __shared__ __align__(16) float sx[C_IN][TH + 2][24]; // 61440 B
    __shared__ __align__(16) float sw[2][32][C_OUT];     // 16384 B ping-pong (8KB halves)

    const int tid = threadIdx.x;
    const int pxg = tid & 31;
    const int cog = tid >> 5;
    const int ly  = pxg >> 2;
    const int lx0 = (pxg & 3) << 2;
    const int b   = blockIdx.z;
    const int gy0 = blockIdx.y * TH;
    const int gx0 = blockIdx.x * TW;

    float bv[8];
#pragma unroll
    for (int o = 0; o < 8; ++o) bv[o] = bias[cog * 8 + o];

    float v[4][8];
#pragma unroll
    for (int p = 0; p < 4; ++p)
#pragma unroll
        for (int o = 0; o < 8; ++o) v[p][o] = 0.0f;

// Async-stage chunk P1 (j = P1>>1, half = P1&1) into sw[P1&1]. 8KB = 2 x 4KB waves'
// worth: per thread 16B; LDS dest is linear in lane order (wave-uniform base rule).
#define ISSUE(P1) do {                                                                     \
    const float* g = wt + ((P1) >> 1) * 4096 + ((P1) & 1) * 2048 + tid * 4;                \
    char* l = ((char*)&sw[(P1) & 1][0][0]) + tid * 16;                                     \
    __builtin_amdgcn_global_load_lds((const __attribute__((address_space(1))) void*)g,     \
                                     (__attribute__((address_space(3))) void*)l, 16, 0, 0);\
    __builtin_amdgcn_global_load_lds((const __attribute__((address_space(1))) void*)(g + 1024), \
                                     (__attribute__((address_space(3))) void*)(l + 4096), 16, 0, 0);\
} while (0)

// Compute one (ky,kx) tap over ci-half HN from sw[HN] (buf index == half index).
#define COMPUTE(KY, KX, HN)                                                                \
    _Pragma("unroll 4")                                                                    \
    for (int ci = 0; ci < 32; ++ci) {                                                      \
        const int cia = (HN) * 32 + ci;                                                    \
        const float4 a = *reinterpret_cast<const float4*>(&sx[cia][ly + (KY)][lx0]);       \
        float xw0, xw1, xw2, xw3;                                                          \
        if ((KX) == 0) { xw0 = a.x; xw1 = a.y; xw2 = a.z; xw3 = a.w; }                     \
        else {                                                                             \
            const float2 c2 = *reinterpret_cast<const float2*>(&sx[cia][ly + (KY)][lx0 + 4]); \
            if ((KX) == 1) { xw0 = a.y; xw1 = a.z; xw2 = a.w; xw3 = c2.x; }                \
            else           { xw0 = a.z; xw1 = a.w; xw2 = c2.x; xw3 = c2.y; }               \
        }                                                                                  \
        const float4 w0 = *reinterpret_cast<const float4*>(&sw[HN][ci][cog * 8]);          \
        const float4 w1 = *reinterpret_cast<const float4*>(&sw[HN][ci][cog * 8 + 4]);      \
        const float wv[8] = {w0.x, w0.y, w0.z, w0.w, w1.x, w1.y, w1.z, w1.w};              \
        const float xwv[4] = {xw0, xw1, xw2, xw3};                                         \
        _Pragma("unroll")                                                                  \
        for (int p = 0; p < 4; ++p)                                                        \
            _Pragma("unroll")                                                              \
            for (int o = 0; o < 8; ++o)                                                    \
                acc[p][o] = fmaf(xwv[p], wv[o], acc[p][o]);                                \
    }

    for (int t = 0; t < T_STEPS; ++t) {
        // prologue: start weight chunk 0 load, then stage x (overlapped)
        ISSUE(0);

        const float* xsrc = x + ((size_t)(t * BATCH + b) * C_IN) * (HH * WW);
        for (int e = tid; e < C_IN * (TH + 2) * 18; e += 256) {
            int ci  = e / ((TH + 2) * 18);
            int rem = e - ci * ((TH + 2) * 18);
            int row = rem / 18;
            int col = rem - row * 18;
            int gy  = gy0 + row - 1;
            int gx  = gx0 + col - 1;
            float val = 0.0f;
            if ((unsigned)gy < (unsigned)HH && (unsigned)gx < (unsigned)WW)
                val = xsrc[ci * (HH * WW) + gy * WW + gx];
            sx[ci][row][col] = val;
        }
        __syncthreads();   // x staged + chunk 0 arrived (vmcnt drained by barrier)

        float acc[4][8];
#pragma unroll
        for (int p = 0; p < 4; ++p)
#pragma unroll
            for (int o = 0; o < 8; ++o) acc[p][o] = 0.0f;

        // 18 phases: issue next chunk, compute current, barrier.
        ISSUE(1);  COMPUTE(0, 0, 0); __syncthreads();
        ISSUE(2);  COMPUTE(0, 0, 1); __syncthreads();
        ISSUE(3);  COMPUTE(0, 1, 0); __syncthreads();
        ISSUE(4);  COMPUTE(0, 1, 1); __syncthreads();
        ISSUE(5);  COMPUTE(0, 2, 0); __syncthreads();
        ISSUE(6);  COMPUTE(0, 2, 1); __syncthreads();
        ISSUE(7);  COMPUTE(1, 0, 0); __syncthreads();
        ISSUE(8);  COMPUTE(1, 0, 1); __syncthreads();
        ISSUE(9);  COMPUTE(1, 1, 0); __syncthreads();
        ISSUE(10); COMPUTE(1, 1, 1); __syncthreads();
        ISSUE(11); COMPUTE(1, 2, 0); __syncthreads();
        ISSUE(12); COMPUTE(1, 2, 1); __syncthreads();
        ISSUE(13); COMPUTE(2, 0, 0); __syncthreads();
        ISSUE(14); COMPUTE(2, 0, 1); __syncthreads();
        ISSUE(15); COMPUTE(2, 1, 0); __syncthreads();
        ISSUE(16); COMPUTE(2, 1, 1); __syncthreads();
        ISSUE(17); COMPUTE(2, 2, 0); __syncthreads();
                   COMPUTE(2, 2, 1); __syncthreads();

        // ---- LIF update (exact f32 op sequence) + spike store ----
        float* obase = out + ((size_t)(t * BATCH + b) * C_OUT + cog * 8) * (HH * WW)
                     + (gy0 + ly) * WW + gx0 + lx0;
#pragma unroll
        for (int o = 0; o < 8; ++o) {
            float sv[4];
#pragma unroll
            for (int p = 0; p < 4; ++p) {
                float cb = __fadd_rn(acc[p][o], bv[o]);                  // conv + bias
                float vt = __fadd_rn(__fmul_rn(v[p][o], DECAY_F32), cb); // v*DECAY + cb
                bool fire = vt > 1.0f;
                sv[p]   = fire ? 1.0f : 0.0f;
                v[p][o] = fire ? 0.0f : vt;                              // soft reset
            }
            float4 s4 = {sv[0], sv[1], sv[2], sv[3]};
            *reinterpret_cast<float4*>(obase + (size_t)o * (HH * WW)) = s4;
        }
    }
#undef COMPUTE
#undef ISSUE
}

extern "C" void kernel_launch(void* const* d_in, const int* in_sizes, int n_in,
                              void* d_out, int out_size, void* d_ws, size_t ws_size,
                              hipStream_t stream) {
    const float* x    = (const float*)d_in[0];
    const float* w    = (const float*)d_in[1];
    const float* bias = (const float*)d_in[2];
    float* out = (float*)d_out;
    float* wt  = (float*)d_ws;   // 9*64*64*4 = 147456 bytes

    hipLaunchKernelGGL(wt_build_kernel, dim3((9 * C_IN * C_OUT + 255) / 256), dim3(256), 0, stream, w, wt);
    hipLaunchKernelGGL(snn_exact_kernel, dim3(WW / TW, HH / TH, BATCH), dim3(256), 0, stream, x, wt, bias, out);
}

// Round 10
// 618.454 us; speedup vs baseline: 1.0436x; 1.0436x over previous
//
#include <hip/hip_runtime.h>

#define T_STEPS 4
#define BATCH   8
#define C_IN    64
#define C_OUT   64
#define HH      128
#define WW      128
#define TH      16
#define TW      16
#define ROWS    (TH + 2)                       // 18
#define RLEN    20                             // padded row (floats), b128-aligned
#define SX_BYTES (C_IN * ROWS * RLEN * 4)      // 92160 B dynamic LDS

// f32 rounding of math.exp(-0.5)
#define DECAY_F32 0.6065306597126334f

// Weight re-layout: w[co][ci][ky][kx] -> wt[j][ci][co], j = ky*3+kx
__global__ void wt_build_kernel(const float* __restrict__ w, float* __restrict__ wt) {
    int tid = blockIdx.x * blockDim.x + threadIdx.x;
    if (tid >= 9 * C_IN * C_OUT) return;
    int co = tid & 63;
    int ci = (tid >> 6) & 63;
    int j  = tid >> 12;
    wt[tid] = w[(co * C_IN + ci) * 9 + j];
}

// Exact replica of the reference f32 arithmetic (probe-verified):
// per output: seq FMA chain over (ky,kx, ci-innermost); cb = acc+bias;
// vt = v*DECAY + cb (separate rounded mul/add); spike = vt>1; soft reset.
// 8 waves; wave w owns co [8w,8w+8) -> weight addresses are wave-uniform
// (readfirstlane'd wid) so they scalarize to s_load + SGPR operands.
// Each lane: 4 px along W (y=lane>>2, xg=lane&3), acc[4px][8co].
__global__ __launch_bounds__(512, 2) void snn_exact_kernel(
    const float* __restrict__ x,    // [T,B,C_IN,H,W]
    const float* __restrict__ wt,   // [9][C_IN][C_OUT]
    const float* __restrict__ bias, // [C_OUT]
    float* __restrict__ out)        // [T,B,C_OUT,H,W]
{
    extern __shared__ float sx[];   // [C_IN][ROWS][RLEN]

    const int tid  = threadIdx.x;
    const int wid  = __builtin_amdgcn_readfirstlane(tid >> 6); // 0..7, SGPR-uniform
    const int lane = tid & 63;
    const int y    = lane >> 2;        // 0..15
    const int lx0  = (lane & 3) << 2;  // 0,4,8,12
    const int b    = blockIdx.z;
    const int gy0  = blockIdx.y * TH;
    const int gx0  = blockIdx.x * TW;
    const int cob  = wid << 3;         // wave's co base

    float bv[8];
#pragma unroll
    for (int o = 0; o < 8; ++o) bv[o] = bias[cob + o];

    float v[4][8];
#pragma unroll
    for (int p = 0; p < 4; ++p)
#pragma unroll
        for (int o = 0; o < 8; ++o) v[p][o] = 0.0f;

    for (int t = 0; t < T_STEPS; ++t) {
        __syncthreads();  // prior t's reads done before overwrite
        const float* xsrc = x + ((size_t)(t * BATCH + b) * C_IN) * (HH * WW);
        for (int e = tid; e < C_IN * ROWS * 18; e += 512) {
            int ci  = e / (ROWS * 18);
            int rem = e - ci * (ROWS * 18);
            int row = rem / 18;
            int col = rem - row * 18;
            int gy  = gy0 + row - 1;
            int gx  = gx0 + col - 1;
            float val = 0.0f;
            if ((unsigned)gy < (unsigned)HH && (unsigned)gx < (unsigned)WW)
                val = xsrc[ci * (HH * WW) + gy * WW + gx];
            sx[(ci * ROWS + row) * RLEN + col] = val;
        }
        __syncthreads();

        float acc[4][8];
#pragma unroll
        for (int p = 0; p < 4; ++p)
#pragma unroll
            for (int o = 0; o < 8; ++o) acc[p][o] = 0.0f;

// One conv tap: ci 0..63 sequential (chain order). Weight ptr wave-uniform.
#define TAP(KY, KX)                                                                   \
        {                                                                             \
            const float* wj = wt + ((KY) * 3 + (KX)) * (C_IN * C_OUT) + cob;          \
            _Pragma("unroll 4")                                                       \
            for (int ci = 0; ci < C_IN; ++ci) {                                       \
                const float* xr = &sx[(ci * ROWS + y + (KY)) * RLEN + lx0];           \
                const float4 a = *reinterpret_cast<const float4*>(xr);                \
                float xw[6];                                                          \
                xw[0] = a.x; xw[1] = a.y; xw[2] = a.z; xw[3] = a.w;                   \
                if ((KX) > 0) {                                                       \
                    const float2 c2 = *reinterpret_cast<const float2*>(xr + 4);       \
                    xw[4] = c2.x; xw[5] = c2.y;                                       \
                } else { xw[4] = 0.f; xw[5] = 0.f; }                                  \
                const float* wp = wj + (ci << 6);                                     \
                float wv[8];                                                          \
                _Pragma("unroll")                                                     \
                for (int o = 0; o < 8; ++o) wv[o] = wp[o];                            \
                _Pragma("unroll")                                                     \
                for (int p = 0; p < 4; ++p)                                           \
                    _Pragma("unroll")                                                 \
                    for (int o = 0; o < 8; ++o)                                       \
                        acc[p][o] = fmaf(xw[p + (KX)], wv[o], acc[p][o]);             \
            }                                                                         \
        }

        TAP(0, 0) TAP(0, 1) TAP(0, 2)
        TAP(1, 0) TAP(1, 1) TAP(1, 2)
        TAP(2, 0) TAP(2, 1) TAP(2, 2)
#undef TAP

        // ---- LIF update (exact f32 op sequence) + spike store ----
        float* obase = out + ((size_t)(t * BATCH + b) * C_OUT + cob) * (HH * WW)
                     + (gy0 + y) * WW + gx0 + lx0;
#pragma unroll
        for (int o = 0; o < 8; ++o) {
            float sv[4];
#pragma unroll
            for (int p = 0; p < 4; ++p) {
                float cb = __fadd_rn(acc[p][o], bv[o]);                  // conv + bias
                float vt = __fadd_rn(__fmul_rn(v[p][o], DECAY_F32), cb); // v*DECAY + cb
                bool fire = vt > 1.0f;
                sv[p]   = fire ? 1.0f : 0.0f;
                v[p][o] = fire ? 0.0f : vt;                              // soft reset
            }
            float4 s4 = {sv[0], sv[1], sv[2], sv[3]};
            *reinterpret_cast<float4*>(obase + (size_t)o * (HH * WW)) = s4;
        }
    }
}

extern "C" void kernel_launch(void* const* d_in, const int* in_sizes, int n_in,
                              void* d_out, int out_size, void* d_ws, size_t ws_size,
                              hipStream_t stream) {
    const float* x    = (const float*)d_in[0];
    const float* w    = (const float*)d_in[1];
    const float* bias = (const float*)d_in[2];
    float* out = (float*)d_out;
    float* wt  = (float*)d_ws;   // 9*64*64*4 = 147456 bytes

    // Allow >64KB dynamic LDS (host-side attribute; not a stream op, capture-safe).
    static_assert(SX_BYTES == 92160, "LDS size");
    (void)hipFuncSetAttribute(reinterpret_cast<const void*>(snn_exact_kernel),
                              hipFuncAttributeMaxDynamicSharedMemorySize, SX_BYTES);

    hipLaunchKernelGGL(wt_build_kernel, dim3((9 * C_IN * C_OUT + 255) / 256), dim3(256), 0, stream, w, wt);
    hipLaunchKernelGGL(snn_exact_kernel, dim3(WW / TW, HH / TH, BATCH), dim3(512), SX_BYTES, stream,
                       x, wt, bias, out);
}

// Round 11
// 485.536 us; speedup vs baseline: 1.3293x; 1.2738x over previous
//
#include <hip/hip_runtime.h>

#define T_STEPS 4
#define BATCH   8
#define C_IN    64
#define C_OUT   64
#define HH      128
#define WW      128
#define TH      4
#define TW      16
#define ROWS    (TH + 2)    // 6
#define RLEN    24          // padded row pitch (words): y-bases {0,24,16,8} mod 32 -> conflict-free

// f32 rounding of math.exp(-0.5)
#define DECAY_F32 0.6065306597126334f

// Weight re-layout: w[co][ci][ky][kx] -> wt[j][ci][co], j = ky*3+kx
__global__ void wt_build_kernel(const float* __restrict__ w, float* __restrict__ wt) {
    int tid = blockIdx.x * blockDim.x + threadIdx.x;
    if (tid >= 9 * C_IN * C_OUT) return;
    int co = tid & 63;
    int ci = (tid >> 6) & 63;
    int j  = tid >> 12;
    wt[tid] = w[(co * C_IN + ci) * 9 + j];
}

// Exact replica of the reference f32 arithmetic (probe-verified variant A):
// per output: seq FMA chain over (ky,kx, ci-innermost); cb = acc+bias;
// vt = v*DECAY + cb (separate rounded mul/add); spike = vt>1; soft reset.
//
// Mapping: block = 8 waves; wave w owns co [8w,8w+8) (weight loads wave-uniform
// -> SGPR). Each lane owns ONE pixel: x = lane>>2 (0..15), y = lane&3 (0..3).
// Per (tap,ci) a lane issues a single ds_read_b32; half-wave bank coverage is
// disjoint (y-base {0,24,16,8} + 8-wide x groups) -> zero conflicts.
// LDS 36864 B -> 4 blocks/CU -> 32 waves/CU.
__global__ __launch_bounds__(512, 8) void snn_exact_kernel(
    const float* __restrict__ x,    // [T,B,C_IN,H,W]
    const float* __restrict__ wt,   // [9][C_IN][C_OUT]
    const float* __restrict__ bias, // [C_OUT]
    float* __restrict__ out)        // [T,B,C_OUT,H,W]
{
    __shared__ __align__(16) float sx[C_IN][ROWS][RLEN];   // 36864 B

    const int tid  = threadIdx.x;
    const int wid  = __builtin_amdgcn_readfirstlane(tid >> 6); // 0..7 (SGPR)
    const int lane = tid & 63;
    const int y    = lane & 3;         // 0..3  (column-major lane order)
    const int xcol = lane >> 2;        // 0..15
    const int b    = blockIdx.z;
    const int gy0  = blockIdx.y * TH;
    const int gx0  = blockIdx.x * TW;
    const int cob  = wid << 3;         // wave's co base

    float bv[8];
#pragma unroll
    for (int o = 0; o < 8; ++o) bv[o] = bias[cob + o];

    float v[8];
#pragma unroll
    for (int o = 0; o < 8; ++o) v[o] = 0.0f;

    for (int t = 0; t < T_STEPS; ++t) {
        __syncthreads();  // prior t's reads done before overwrite
        const float* xsrc = x + ((size_t)(t * BATCH + b) * C_IN) * (HH * WW);
        for (int e = tid; e < C_IN * ROWS * 18; e += 512) {
            int ci  = e / (ROWS * 18);
            int rem = e - ci * (ROWS * 18);
            int row = rem / 18;
            int col = rem - row * 18;
            int gy  = gy0 + row - 1;
            int gx  = gx0 + col - 1;
            float val = 0.0f;
            if ((unsigned)gy < (unsigned)HH && (unsigned)gx < (unsigned)WW)
                val = xsrc[ci * (HH * WW) + gy * WW + gx];
            sx[ci][row][col] = val;
        }
        __syncthreads();

        float acc[8];
#pragma unroll
        for (int o = 0; o < 8; ++o) acc[o] = 0.0f;

// One conv tap: ci 0..63 sequential (exact chain order). One ds_read_b32 per
// (ci): sx[ci][y+KY][xcol+KX]. Weight ptr wave-uniform -> s_load_dwordx8.
#define TAP(KY, KX)                                                                   \
        {                                                                             \
            const float* wj = wt + ((KY) * 3 + (KX)) * (C_IN * C_OUT) + cob;          \
            _Pragma("unroll 4")                                                       \
            for (int ci = 0; ci < C_IN; ++ci) {                                       \
                const float xv = sx[ci][y + (KY)][xcol + (KX)];                       \
                const float* wp = wj + (ci << 6);                                     \
                _Pragma("unroll")                                                     \
                for (int o = 0; o < 8; ++o)                                           \
                    acc[o] = fmaf(xv, wp[o], acc[o]);                                 \
            }                                                                         \
        }

        TAP(0, 0) TAP(0, 1) TAP(0, 2)
        TAP(1, 0) TAP(1, 1) TAP(1, 2)
        TAP(2, 0) TAP(2, 1) TAP(2, 2)
#undef TAP

        // ---- LIF update (exact f32 op sequence) + spike store ----
        float* obase = out + ((size_t)(t * BATCH + b) * C_OUT + cob) * (HH * WW)
                     + (gy0 + y) * WW + gx0 + xcol;
#pragma unroll
        for (int o = 0; o < 8; ++o) {
            float cb = __fadd_rn(acc[o], bv[o]);                  // conv + bias
            float vt = __fadd_rn(__fmul_rn(v[o], DECAY_F32), cb); // v*DECAY + cb
            bool fire = vt > 1.0f;
            v[o] = fire ? 0.0f : vt;                              // soft reset
            obase[(size_t)o * (HH * WW)] = fire ? 1.0f : 0.0f;
        }
    }
}

extern "C" void kernel_launch(void* const* d_in, const int* in_sizes, int n_in,
                              void* d_out, int out_size, void* d_ws, size_t ws_size,
                              hipStream_t stream) {
    const float* x    = (const float*)d_in[0];
    const float* w    = (const float*)d_in[1];
    const float* bias = (const float*)d_in[2];
    float* out = (float*)d_out;
    float* wt  = (float*)d_ws;   // 9*64*64*4 = 147456 bytes

    hipLaunchKernelGGL(wt_build_kernel, dim3((9 * C_IN * C_OUT + 255) / 256), dim3(256), 0, stream, w, wt);
    hipLaunchKernelGGL(snn_exact_kernel, dim3(WW / TW, HH / TH, BATCH), dim3(512), 0, stream,
                       x, wt, bias, out);
}

// Round 12
// 478.445 us; speedup vs baseline: 1.3490x; 1.0148x over previous
//
#include <hip/hip_runtime.h>

#define T_STEPS 4
#define BATCH   8
#define C_IN    64
#define C_OUT   64
#define HH      128
#define WW      128
#define TH      8           // block tile height (2 wave-strips of 4)
#define TW      16
#define ROWS    (TH + 2)    // 10
#define RLEN    24          // padded row pitch (words) -> 2-way banks everywhere (free)

// f32 rounding of math.exp(-0.5)
#define DECAY_F32 0.6065306597126334f

// Weight re-layout: w[co][ci][ky][kx] -> wt[j][ci][co], j = ky*3+kx
__global__ void wt_build_kernel(const float* __restrict__ w, float* __restrict__ wt) {
    int tid = blockIdx.x * blockDim.x + threadIdx.x;
    if (tid >= 9 * C_IN * C_OUT) return;
    int co = tid & 63;
    int ci = (tid >> 6) & 63;
    int j  = tid >> 12;
    wt[tid] = w[(co * C_IN + ci) * 9 + j];
}

// Exact replica of the reference f32 arithmetic (probe-verified variant A):
// per output: seq FMA chain over (ky,kx, ci-innermost); cb = acc+bias;
// vt = v*DECAY + cb (separate rounded mul/add); spike = vt>1; soft reset.
//
// Block = 512 thr = 8 waves. Wave w: y-strip sy = (w>>2)*4, co base = (w&3)*16.
// Lane owns ONE pixel (y = lane&3 within strip, x = lane>>2) and 16 c_out.
// Per (tap,ci): one ds_read_b32 (conflict-free mapping) + 16 FMA with
// SGPR-broadcast weights (wave-uniform address -> s_load_dwordx16).
__global__ __launch_bounds__(512, 2) void snn_exact_kernel(
    const float* __restrict__ x,    // [T,B,C_IN,H,W]
    const float* __restrict__ wt,   // [9][C_IN][C_OUT]
    const float* __restrict__ bias, // [C_OUT]
    float* __restrict__ out)        // [T,B,C_OUT,H,W]
{
    __shared__ __align__(16) float sx[C_IN][ROWS][RLEN];   // 61440 B

    const int tid  = threadIdx.x;
    const int wid  = __builtin_amdgcn_readfirstlane(tid >> 6); // 0..7 (SGPR)
    const int lane = tid & 63;
    const int y    = lane & 3;          // 0..3 within strip
    const int xcol = lane >> 2;         // 0..15
    const int sy   = (wid >> 2) << 2;   // strip base: 0 or 4
    const int cob  = (wid & 3) << 4;    // wave's co base: 0,16,32,48
    const int b    = blockIdx.z;
    const int gy0  = blockIdx.y * TH;
    const int gx0  = blockIdx.x * TW;

    float bv[16];
#pragma unroll
    for (int o = 0; o < 16; ++o) bv[o] = bias[cob + o];

    float v[16];
#pragma unroll
    for (int o = 0; o < 16; ++o) v[o] = 0.0f;

    for (int t = 0; t < T_STEPS; ++t) {
        __syncthreads();  // prior t's reads done before overwrite
        const float* xsrc = x + ((size_t)(t * BATCH + b) * C_IN) * (HH * WW);
        for (int e = tid; e < C_IN * ROWS * 18; e += 512) {
            int ci  = e / (ROWS * 18);
            int rem = e - ci * (ROWS * 18);
            int row = rem / 18;
            int col = rem - row * 18;
            int gy  = gy0 + row - 1;
            int gx  = gx0 + col - 1;
            float val = 0.0f;
            if ((unsigned)gy < (unsigned)HH && (unsigned)gx < (unsigned)WW)
                val = xsrc[ci * (HH * WW) + gy * WW + gx];
            sx[ci][row][col] = val;
        }
        __syncthreads();

        float acc[16];
#pragma unroll
        for (int o = 0; o < 16; ++o) acc[o] = 0.0f;

// One conv tap: ci 0..63 sequential (exact chain order). One ds_read_b32 per ci,
// 16 FMAs with SGPR weights.
#define TAP(KY, KX)                                                                   \
        {                                                                             \
            const float* wj = wt + ((KY) * 3 + (KX)) * (C_IN * C_OUT) + cob;          \
            _Pragma("unroll 4")                                                       \
            for (int ci = 0; ci < C_IN; ++ci) {                                       \
                const float xv = sx[ci][sy + y + (KY)][xcol + (KX)];                  \
                const float* wp = wj + (ci << 6);                                     \
                _Pragma("unroll")                                                     \
                for (int o = 0; o < 16; ++o)                                          \
                    acc[o] = fmaf(xv, wp[o], acc[o]);                                 \
            }                                                                         \
        }

        TAP(0, 0) TAP(0, 1) TAP(0, 2)
        TAP(1, 0) TAP(1, 1) TAP(1, 2)
        TAP(2, 0) TAP(2, 1) TAP(2, 2)
#undef TAP

        // ---- LIF update (exact f32 op sequence) + spike store ----
        float* obase = out + ((size_t)(t * BATCH + b) * C_OUT + cob) * (HH * WW)
                     + (gy0 + sy + y) * WW + gx0 + xcol;
#pragma unroll
        for (int o = 0; o < 16; ++o) {
            float cb = __fadd_rn(acc[o], bv[o]);                  // conv + bias
            float vt = __fadd_rn(__fmul_rn(v[o], DECAY_F32), cb); // v*DECAY + cb
            bool fire = vt > 1.0f;
            v[o] = fire ? 0.0f : vt;                              // soft reset
            obase[(size_t)o * (HH * WW)] = fire ? 1.0f : 0.0f;
        }
    }
}

extern "C" void kernel_launch(void* const* d_in, const int* in_sizes, int n_in,
                              void* d_out, int out_size, void* d_ws, size_t ws_size,
                              hipStream_t stream) {
    const float* x    = (const float*)d_in[0];
    const float* w    = (const float*)d_in[1];
    const float* bias = (const float*)d_in[2];
    float* out = (float*)d_out;
    float* wt  = (float*)d_ws;   // 9*64*64*4 = 147456 bytes

    hipLaunchKernelGGL(wt_build_kernel, dim3((9 * C_IN * C_OUT + 255) / 256), dim3(256), 0, stream, w, wt);
    hipLaunchKernelGGL(snn_exact_kernel, dim3(WW / TW, HH / TH, BATCH), dim3(512), 0, stream,
                       x, wt, bias, out);
}